// Round 1
// 279.795 us; speedup vs baseline: 1.1740x; 1.1740x over previous
//
#include <hip/hip_runtime.h>

// Problem constants
#define BB 32
#define CC 128
#define HW 1024            // 32*32
#define NN 32768           // BB*HW
#define KK 1024            // num embeddings
#define DD 128             // embedding dim
// Output offsets (floats): (loss, quantized_nchw, perplexity, encodings, top_k_quantized)
#define OFF_QUANT 1
#define OFF_PERP  4194305
#define OFF_ENC   4194306
#define OFF_TOPK  37748738

// ws layout (bytes) — offsets preserved from prior session
#define WS_PARTIALS 0          // 512 doubles used
#define WS_HIST     32768      // 1024 ints
#define WS_TOP3     1085440    // 32768*4 ints = 512 KiB
#define WS_EMBBF    1609728    // 1024*128 ushort = 256 KiB
#define WS_ENORM    1871872    // 1024 float = 4 KiB

typedef __attribute__((ext_vector_type(8))) short short8;
typedef __attribute__((ext_vector_type(4))) float f32x4;
typedef __attribute__((ext_vector_type(2))) float f32x2;

__device__ __forceinline__ ushort f32_to_bf16(float v) {
    uint u = __float_as_uint(v);
    u = (u + 0x7FFFu + ((u >> 16) & 1u)) >> 16;   // RNE
    return (ushort)u;
}

// ---------------------------------------------------------------------------
// kP_emb: emb fp32 -> bf16 + fp32 row norms. Block 0 zeroes the histogram.
// (x-half of the old prep kernel is gone: the fused kernel reads NCHW direct.)
// ---------------------------------------------------------------------------
__global__ __launch_bounds__(256) void kP_emb(
    const float* __restrict__ emb, ushort* __restrict__ embbf,
    float* __restrict__ enorm, int* __restrict__ hist)
{
    const int blk = blockIdx.x, t = threadIdx.x;
    const int rr = t >> 2, q = t & 3;
    const int row = blk * 64 + rr;
    const float4* src = (const float4*)(emb + (size_t)row * 128 + q * 32);
    short8* dst = (short8*)(embbf + (size_t)row * 128 + q * 32);
    float nrm = 0.f;
#pragma unroll
    for (int u2 = 0; u2 < 4; ++u2) {
        float4 a = src[u2 * 2], b2 = src[u2 * 2 + 1];
        float f[8] = {a.x, a.y, a.z, a.w, b2.x, b2.y, b2.z, b2.w};
        union { short8 v; ushort u[8]; } p;
#pragma unroll
        for (int j = 0; j < 8; ++j) {
            nrm = fmaf(f[j], f[j], nrm);
            p.u[j] = f32_to_bf16(f[j]);
        }
        dst[u2] = p.v;
    }
    nrm += __shfl_xor(nrm, 1);
    nrm += __shfl_xor(nrm, 2);
    if (q == 0) enorm[row] = nrm;
    if (blk == 0)
        for (int i = t; i < 1024; i += 256) hist[i] = 0;
}

// ---------------------------------------------------------------------------
// kA2B: fused candidate pass + exact refine. 512 blocks x 256 threads
// (4 waves, 16 rows/wave -> 8 waves/CU = 2/SIMD, vs 1/SIMD before).
//   phase 1: A-frags direct from global NCHW (line-aligned 64B reads), bf16
//   phase 2: MFMA over 8 emb tiles (LDS, XOR-swizzled), per-lane top-3 keys
//   phase 3: per-row merge of 48 keys -> top-8 candidates (LDS broadcast)
//   phase 4: stage fp32 x in LDS (union with emb tile), fp64 refine -> top-3,
//            3rd-idx histogram, per-block fp64 loss partial
// ---------------------------------------------------------------------------
__global__ __launch_bounds__(256) void kA2B(
    const float* __restrict__ in, const float* __restrict__ emb,
    const ushort* __restrict__ embbf, const float* __restrict__ enorm,
    int* __restrict__ top3, int* __restrict__ hist, double* __restrict__ partials)
{
    __shared__ union {
        float xs[128 * 66];     // 33792B: fp32 x tile for the exact refine
        uint4 et16[2048];       // 32768B: one 128-row bf16 emb tile (and keybuf)
    } sh;
    __shared__ float enl[1024];
    __shared__ double lsum[64];
    __shared__ int cbuf[512];   // top-8 candidate indices per row

    const int t = threadIdx.x;
    const int lane = t & 63, w = t >> 6;
    const int quad = lane >> 4, m = lane & 15;
    const int rowBase = blockIdx.x * 64;
    const int b = rowBase >> 10, hw0 = rowBase & 1023;
    const float* inB = in + (size_t)b * (CC * HW) + hw0;

    for (int i = t; i < 1024; i += 256) enl[i] = enorm[i];

    // ---- phase 1: A fragments direct from global (no xbf round-trip) ----
    short8 A[4];
    {
        const int ra = w * 16 + m;
#pragma unroll
        for (int kk = 0; kk < 4; ++kk) {
            union { short8 v; ushort u[8]; } p;
#pragma unroll
            for (int j = 0; j < 8; ++j)
                p.u[j] = f32_to_bf16(inB[(size_t)(kk * 32 + quad * 8 + j) * HW + ra]);
            A[kk] = p.v;
        }
    }

    uint kq[4][3];
#pragma unroll
    for (int i = 0; i < 4; ++i)
        kq[i][0] = kq[i][1] = kq[i][2] = 0xFFFFFFFFu;

    const uint4* eg = (const uint4*)embbf;

    // ---- phase 2: MFMA candidate pass ----
    for (int tile = 0; tile < 8; ++tile) {
        __syncthreads();
#pragma unroll
        for (int u = 0; u < 8; ++u) {
            int c = u * 256 + t;
            int row = c >> 4, kb = c & 15;
            sh.et16[row * 16 + (kb ^ (row & 7))] = eg[(size_t)(tile * 128 + row) * 16 + kb];
        }
        __syncthreads();
#pragma unroll
        for (int sp = 0; sp < 4; ++sp) {     // sub-pairs: two independent acc chains
            f32x4 acc0 = {0.f, 0.f, 0.f, 0.f}, acc1 = {0.f, 0.f, 0.f, 0.f};
#pragma unroll
            for (int kk = 0; kk < 4; ++kk) {
                int sl = (kk * 4 + quad) ^ (m & 7);
                short8 B0 = *(const short8*)&sh.et16[((sp * 2)     * 16 + m) * 16 + sl];
                short8 B1 = *(const short8*)&sh.et16[((sp * 2 + 1) * 16 + m) * 16 + sl];
                acc0 = __builtin_amdgcn_mfma_f32_16x16x32_bf16(A[kk], B0, acc0, 0, 0, 0);
                acc1 = __builtin_amdgcn_mfma_f32_16x16x32_bf16(A[kk], B1, acc1, 0, 0, 0);
            }
            const int col0 = tile * 128 + (sp * 2) * 16 + m;
            const float en0 = enl[col0], en1 = enl[col0 + 16];
#pragma unroll
            for (int i = 0; i < 4; ++i) {
                {
                    float sc = fmaf(-2.f, acc0[i], en0);
                    uint u_ = __float_as_uint(sc);
                    u_ ^= (uint)(((int)u_) >> 31) | 0x80000000u;   // sortable
                    uint key = (u_ & 0xFFFFFC00u) | (uint)col0;
                    uint t0 = max(kq[i][0], key); kq[i][0] = min(kq[i][0], key);
                    uint t1 = max(kq[i][1], t0);  kq[i][1] = min(kq[i][1], t0);
                    kq[i][2] = min(kq[i][2], t1);
                }
                {
                    float sc = fmaf(-2.f, acc1[i], en1);
                    uint u_ = __float_as_uint(sc);
                    u_ ^= (uint)(((int)u_) >> 31) | 0x80000000u;
                    uint key = (u_ & 0xFFFFFC00u) | (uint)(col0 + 16);
                    uint t0 = max(kq[i][0], key); kq[i][0] = min(kq[i][0], key);
                    uint t1 = max(kq[i][1], t0);  kq[i][1] = min(kq[i][1], t0);
                    kq[i][2] = min(kq[i][2], t1);
                }
            }
        }
    }

    // ---- phase 3: per-row merge of 48 keys -> top-8 candidates ----
    __syncthreads();
    uint* keybuf = (uint*)sh.et16;            // et16 free; 48*65*4B = 12.5KB
#pragma unroll
    for (int i = 0; i < 4; ++i) {
        int rowl = w * 16 + quad * 4 + i;
#pragma unroll
        for (int j = 0; j < 3; ++j)
            keybuf[(m * 3 + j) * 65 + rowl] = kq[i][j];
    }
    __syncthreads();

    if (t < 64) {
        uint D[8];
#pragma unroll
        for (int s = 0; s < 8; ++s) D[s] = 0xFFFFFFFFu;
        for (int s = 0; s < 48; ++s) {
            uint k = keybuf[s * 65 + t];
            if (k < D[7]) {
                D[7] = k;
#pragma unroll
                for (int u = 7; u > 0; --u)
                    if (D[u] < D[u - 1]) { uint tmp = D[u]; D[u] = D[u - 1]; D[u - 1] = tmp; }
            }
        }
#pragma unroll
        for (int s = 0; s < 8; ++s) cbuf[t * 8 + s] = (int)(D[s] & 1023u);
    }
    __syncthreads();

    // ---- phase 4: stage fp32 x (overwrites emb tile), fp64 exact refine ----
    for (int i = t; i < 8192; i += 256) {
        int c = i >> 6, r2 = i & 63;
        sh.xs[c * 66 + r2] = inB[(size_t)c * HW + r2];
    }
    __syncthreads();

    const int r = t >> 2;     // row 0..63
    const int q = t & 3;      // c-chunk of 32
    const int n = rowBase + r;

    double dist[8]; int es[8];
#pragma unroll
    for (int s = 0; s < 8; ++s) {
        int e = cbuf[r * 8 + s];
        es[s] = e;
        const float4* er = (const float4*)(emb + (size_t)e * DD + q * 32);
        double acc = 0.0;
#pragma unroll
        for (int u = 0; u < 8; ++u) {
            float4 ev = er[u];
            int c0 = q * 32 + u * 4;
            double a0 = (double)sh.xs[(c0 + 0) * 66 + r] - (double)ev.x;
            double a1 = (double)sh.xs[(c0 + 1) * 66 + r] - (double)ev.y;
            double a2 = (double)sh.xs[(c0 + 2) * 66 + r] - (double)ev.z;
            double a3 = (double)sh.xs[(c0 + 3) * 66 + r] - (double)ev.w;
            acc += a0 * a0 + a1 * a1 + a2 * a2 + a3 * a3;
        }
        acc += __shfl_xor(acc, 1);
        acc += __shfl_xor(acc, 2);
        dist[s] = acc;
    }

    if (q == 0) {
        unsigned usedm = 0;   // bitmask (no runtime-indexed array -> no scratch)
        int out_idx[3];
        double d_top1 = 0.0;
#pragma unroll
        for (int p = 0; p < 3; ++p) {
            double bd = 1.0e300; int bi = 0x7fffffff, bs = 0;
#pragma unroll
            for (int s = 0; s < 8; ++s) {
                if ((usedm >> s) & 1u) continue;
                if (dist[s] < bd || (dist[s] == bd && es[s] < bi)) {
                    bd = dist[s]; bi = es[s]; bs = s;
                }
            }
            usedm |= (1u << bs);
            out_idx[p] = bi;
            if (p == 0) d_top1 = bd;
        }
        top3[n * 4 + 0] = out_idx[0];
        top3[n * 4 + 1] = out_idx[1];
        top3[n * 4 + 2] = out_idx[2];
        atomicAdd(&hist[out_idx[2]], 1);
        lsum[r] = d_top1;
    }
    __syncthreads();
    if (t < 8) {
        double a = 0.0;
#pragma unroll
        for (int i2 = 0; i2 < 8; ++i2) a += lsum[t * 8 + i2];
        lsum[t] = a;
    }
    __syncthreads();
    if (t == 0) {
        double a = 0.0;
#pragma unroll
        for (int i2 = 0; i2 < 8; ++i2) a += lsum[i2];
        partials[blockIdx.x] = a;
    }
}

// ---------------------------------------------------------------------------
// kEpi: fused epilogue — one pass over all 201 MB of big outputs.
//   blocks 0..1023    : quantized_nchw. Emb COLUMNS staged in LDS (coalesced
//                       float4 reads) instead of per-store 64-line L2 gathers.
//   blocks 1024..4095 : top_k_quantized (f32x2; OFF_TOPK is 8-mod-16 aligned)
//   blocks 4096..8191 : encodings one-hot (f32x2; OFF_ENC is 8-mod-16 aligned)
//   block 8192        : finalize loss + perplexity (fp64)
// Plain stores: L2 write-back coalesces lines (nontemporal inflated HBM
// writes 3.5x and capped BW at 1.7 TB/s — prior-session evidence).
// ---------------------------------------------------------------------------
__global__ __launch_bounds__(256) void kEpi(
    const float* __restrict__ emb, const int* __restrict__ top3,
    const double* __restrict__ partials, const int* __restrict__ hist,
    float* __restrict__ out)
{
    __shared__ union {
        float cols[4][1024];   // 16KB emb columns (quantized branch)
        int e8[8];
        double sred[256];
    } sh;
    const int blk = blockIdx.x, t = threadIdx.x;
    if (blk < 1024) {
        // quantized: block covers b=blk>>5, channels c0..c0+3, all 1024 hw.
        float* dst = out + OFF_QUANT;
        const int bb = blk >> 5;
        const int c0 = (4 * blk) & 127;
#pragma unroll
        for (int k = 0; k < 4; ++k) {       // stage emb[:, c0..c0+3] -> LDS
            int e = k * 256 + t;
            float4 f4 = *(const float4*)(emb + (size_t)e * DD + c0);
            sh.cols[0][e] = f4.x; sh.cols[1][e] = f4.y;
            sh.cols[2][e] = f4.z; sh.cols[3][e] = f4.w;
        }
        int e4[4];
#pragma unroll
        for (int v = 0; v < 4; ++v)
            e4[v] = top3[(bb * 1024 + v * 256 + t) * 4];
        __syncthreads();
#pragma unroll 4
        for (int u = 0; u < 16; ++u) {
            int j = blk * 4096 + u * 256 + t;
            dst[j] = sh.cols[u >> 2][e4[u & 3]];
        }
    } else if (blk < 4096) {
        // top_k_quantized: 6.29M f32x2, contiguous 256-f32x2 runs per instr
        const f32x2* e2 = (const f32x2*)emb;
        f32x2* dst = (f32x2*)(out + OFF_TOPK);
#pragma unroll 4
        for (int u = 0; u < 8; ++u) {
            int j  = (blk - 1024) * 2048 + u * 256 + t;
            int c2 = j & 63;
            int n  = (j >> 6) & 32767;
            int k  = j >> 21;
            int e  = top3[n * 4 + k];
            dst[j] = e2[e * 64 + c2];
        }
    } else if (blk < 8192) {
        // encodings: 8 rows/block; each instruction a contiguous 2KB wave-run.
        const int row0 = (blk - 4096) * 8;
        if (t < 8) sh.e8[t] = top3[(row0 + t) * 4 + 2];
        __syncthreads();
        f32x2* dst = (f32x2*)(out + OFF_ENC) + (size_t)row0 * 512;
#pragma unroll 4
        for (int u = 0; u < 16; ++u) {
            int idx = u * 256 + t;
            int e = sh.e8[idx >> 9];
            int col = idx & 511;
            f32x2 v = {0.f, 0.f};
            if ((e >> 1) == col) v[e & 1] = 1.0f;
            dst[idx] = v;
        }
    } else {
        // finals: loss from 512 partials, perplexity from 1024-bin hist
        sh.sred[t] = partials[t] + partials[t + 256];
        __syncthreads();
        for (int s = 128; s > 0; s >>= 1) {
            if (t < s) sh.sred[t] += sh.sred[t + s];
            __syncthreads();
        }
        if (t == 0) out[0] = (float)(0.25 * sh.sred[0] / 4194304.0);
        __syncthreads();
        double s2 = 0.0;
#pragma unroll
        for (int i = 0; i < 4; ++i) {
            double p = (double)hist[t + i * 256] * (1.0 / 32768.0);
            s2 += p * log(p + 1e-10);
        }
        sh.sred[t] = s2;
        __syncthreads();
        for (int s = 128; s > 0; s >>= 1) {
            if (t < s) sh.sred[t] += sh.sred[t + s];
            __syncthreads();
        }
        if (t == 0) out[OFF_PERP] = (float)exp(-sh.sred[0]);
    }
}

extern "C" void kernel_launch(void* const* d_in, const int* in_sizes, int n_in,
                              void* d_out, int out_size, void* d_ws, size_t ws_size,
                              hipStream_t stream)
{
    const float* in  = (const float*)d_in[0];
    const float* emb = (const float*)d_in[1];
    float* out = (float*)d_out;
    char*  ws  = (char*)d_ws;

    double* partials = (double*)(ws + WS_PARTIALS);
    int*    hist     = (int*)(ws + WS_HIST);
    int*    top3     = (int*)(ws + WS_TOP3);
    ushort* embbf    = (ushort*)(ws + WS_EMBBF);
    float*  enorm    = (float*)(ws + WS_ENORM);

    kP_emb<<<dim3(16),   dim3(256), 0, stream>>>(emb, embbf, enorm, hist);
    kA2B  <<<dim3(512),  dim3(256), 0, stream>>>(in, emb, embbf, enorm, top3, hist, partials);
    kEpi  <<<dim3(8193), dim3(256), 0, stream>>>(emb, top3, partials, hist, out);
}

// Round 2
// 266.658 us; speedup vs baseline: 1.2318x; 1.0493x over previous
//
#include <hip/hip_runtime.h>

// Problem constants
#define BB 32
#define CC 128
#define HW 1024            // 32*32
#define NN 32768           // BB*HW
#define KK 1024            // num embeddings
#define DD 128             // embedding dim
// Output offsets (floats): (loss, quantized_nchw, perplexity, encodings, top_k_quantized)
#define OFF_QUANT 1
#define OFF_PERP  4194305
#define OFF_ENC   4194306
#define OFF_TOPK  37748738

// ws layout (bytes)
#define WS_PARTIALS 0          // 512 doubles used
#define WS_HIST     32768      // 1024 ints
#define WS_EMBBF    1609728    // 1024*128 ushort = 256 KiB
#define WS_ENORM    1871872    // 1024 float = 4 KiB

typedef __attribute__((ext_vector_type(8))) short short8;
typedef __attribute__((ext_vector_type(4))) float f32x4;
typedef __attribute__((ext_vector_type(2))) float f32x2;

__device__ __forceinline__ ushort f32_to_bf16(float v) {
    uint u = __float_as_uint(v);
    u = (u + 0x7FFFu + ((u >> 16) & 1u)) >> 16;   // RNE
    return (ushort)u;
}

// ---------------------------------------------------------------------------
// kP_emb: emb fp32 -> bf16 + fp32 row norms. Block 0 zeroes the histogram.
// ---------------------------------------------------------------------------
__global__ __launch_bounds__(256) void kP_emb(
    const float* __restrict__ emb, ushort* __restrict__ embbf,
    float* __restrict__ enorm, int* __restrict__ hist)
{
    const int blk = blockIdx.x, t = threadIdx.x;
    const int rr = t >> 2, q = t & 3;
    const int row = blk * 64 + rr;
    const float4* src = (const float4*)(emb + (size_t)row * 128 + q * 32);
    short8* dst = (short8*)(embbf + (size_t)row * 128 + q * 32);
    float nrm = 0.f;
#pragma unroll
    for (int u2 = 0; u2 < 4; ++u2) {
        float4 a = src[u2 * 2], b2 = src[u2 * 2 + 1];
        float f[8] = {a.x, a.y, a.z, a.w, b2.x, b2.y, b2.z, b2.w};
        union { short8 v; ushort u[8]; } p;
#pragma unroll
        for (int j = 0; j < 8; ++j) {
            nrm = fmaf(f[j], f[j], nrm);
            p.u[j] = f32_to_bf16(f[j]);
        }
        dst[u2] = p.v;
    }
    nrm += __shfl_xor(nrm, 1);
    nrm += __shfl_xor(nrm, 2);
    if (q == 0) enorm[row] = nrm;
    if (blk == 0)
        for (int i = t; i < 1024; i += 256) hist[i] = 0;
}

// ---------------------------------------------------------------------------
// kFull: everything per 64-row slab. 512 blocks x 256 threads (2 blocks/CU,
// 74KB LDS). Phases:
//   0: stage x fp32 -> LDS (coalesced 256B runs; single global read of x)
//   1: bf16 A-fragments built from LDS
//   2: MFMA over 8 emb tiles (LDS, XOR-swizzled), per-lane top-3 keys
//   3: per-row merge of 48 keys -> top-8 candidates
//   4: fp64 exact refine -> top-3 (tie-break lower idx), hist + loss partial
//   5: fused output writes (quantized / top_k_quantized / encodings) straight
//      from LDS top-3 — no top3 round-trip, no separate epilogue dispatch.
// Plain stores throughout: L2 write-back coalesces lines (nontemporal
// inflated HBM writes 3.5x — prior-session evidence).
// ---------------------------------------------------------------------------
__global__ __launch_bounds__(256) void kFull(
    const float* __restrict__ in, const float* __restrict__ emb,
    const ushort* __restrict__ embbf, const float* __restrict__ enorm,
    int* __restrict__ hist, double* __restrict__ partials,
    float* __restrict__ out)
{
    __shared__ float xs[128 * 66];      // 33792B fp32 x tile [c][r], stride 66
    __shared__ union {
        uint4 et16[2048];               // 32768B emb bf16 tile (MFMA phase)
        uint  kb[8192];                 // keybuf for the merge phase
    } sh;
    __shared__ float enl[1024];
    __shared__ double lsum[64];
    __shared__ int cbuf[512];           // top-8 candidate indices per row
    __shared__ int s_top[3][64];        // final top-3 per row

    const int t = threadIdx.x;
    const int lane = t & 63, w = t >> 6;
    const int quad = lane >> 4, m = lane & 15;
    const int rowBase = blockIdx.x * 64;
    const int b = rowBase >> 10, hw0 = rowBase & 1023;
    const float* inB = in + (size_t)b * (CC * HW) + hw0;

    // ---- phase 0: stage x (coalesced) ----
    for (int i = t; i < 8192; i += 256) {
        int c = i >> 6, r2 = i & 63;
        xs[c * 66 + r2] = inB[(size_t)c * HW + r2];
    }
    for (int i = t; i < 1024; i += 256) enl[i] = enorm[i];
    __syncthreads();

    // ---- phase 1: A fragments from LDS (2-way bank alias = free) ----
    short8 A[4];
    {
        const int ra = w * 16 + m;
#pragma unroll
        for (int kk = 0; kk < 4; ++kk) {
            union { short8 v; ushort u[8]; } p;
#pragma unroll
            for (int j = 0; j < 8; ++j)
                p.u[j] = f32_to_bf16(xs[(kk * 32 + quad * 8 + j) * 66 + ra]);
            A[kk] = p.v;
        }
    }

    uint kq[4][3];
#pragma unroll
    for (int i = 0; i < 4; ++i)
        kq[i][0] = kq[i][1] = kq[i][2] = 0xFFFFFFFFu;

    const uint4* eg = (const uint4*)embbf;

    // ---- phase 2: MFMA candidate pass ----
    for (int tile = 0; tile < 8; ++tile) {
        __syncthreads();
#pragma unroll
        for (int u = 0; u < 8; ++u) {
            int c = u * 256 + t;
            int row = c >> 4, kb2 = c & 15;
            sh.et16[row * 16 + (kb2 ^ (row & 7))] = eg[(size_t)(tile * 128 + row) * 16 + kb2];
        }
        __syncthreads();
#pragma unroll
        for (int sp = 0; sp < 4; ++sp) {     // two independent acc chains
            f32x4 acc0 = {0.f, 0.f, 0.f, 0.f}, acc1 = {0.f, 0.f, 0.f, 0.f};
#pragma unroll
            for (int kk = 0; kk < 4; ++kk) {
                int sl = (kk * 4 + quad) ^ (m & 7);
                short8 B0 = *(const short8*)&sh.et16[((sp * 2)     * 16 + m) * 16 + sl];
                short8 B1 = *(const short8*)&sh.et16[((sp * 2 + 1) * 16 + m) * 16 + sl];
                acc0 = __builtin_amdgcn_mfma_f32_16x16x32_bf16(A[kk], B0, acc0, 0, 0, 0);
                acc1 = __builtin_amdgcn_mfma_f32_16x16x32_bf16(A[kk], B1, acc1, 0, 0, 0);
            }
            const int col0 = tile * 128 + (sp * 2) * 16 + m;
            const float en0 = enl[col0], en1 = enl[col0 + 16];
#pragma unroll
            for (int i = 0; i < 4; ++i) {
                {
                    float sc = fmaf(-2.f, acc0[i], en0);
                    uint u_ = __float_as_uint(sc);
                    u_ ^= (uint)(((int)u_) >> 31) | 0x80000000u;   // sortable
                    uint key = (u_ & 0xFFFFFC00u) | (uint)col0;
                    uint t0 = max(kq[i][0], key); kq[i][0] = min(kq[i][0], key);
                    uint t1 = max(kq[i][1], t0);  kq[i][1] = min(kq[i][1], t0);
                    kq[i][2] = min(kq[i][2], t1);
                }
                {
                    float sc = fmaf(-2.f, acc1[i], en1);
                    uint u_ = __float_as_uint(sc);
                    u_ ^= (uint)(((int)u_) >> 31) | 0x80000000u;
                    uint key = (u_ & 0xFFFFFC00u) | (uint)(col0 + 16);
                    uint t0 = max(kq[i][0], key); kq[i][0] = min(kq[i][0], key);
                    uint t1 = max(kq[i][1], t0);  kq[i][1] = min(kq[i][1], t0);
                    kq[i][2] = min(kq[i][2], t1);
                }
            }
        }
    }

    // ---- phase 3: per-row merge of 48 keys -> top-8 candidates ----
    __syncthreads();
#pragma unroll
    for (int i = 0; i < 4; ++i) {
        int rowl = w * 16 + quad * 4 + i;
#pragma unroll
        for (int j = 0; j < 3; ++j)
            sh.kb[(m * 3 + j) * 65 + rowl] = kq[i][j];
    }
    __syncthreads();

    if (t < 64) {
        uint D[8];
#pragma unroll
        for (int s = 0; s < 8; ++s) D[s] = 0xFFFFFFFFu;
        for (int s = 0; s < 48; ++s) {
            uint k = sh.kb[s * 65 + t];
            if (k < D[7]) {
                D[7] = k;
#pragma unroll
                for (int u = 7; u > 0; --u)
                    if (D[u] < D[u - 1]) { uint tmp = D[u]; D[u] = D[u - 1]; D[u - 1] = tmp; }
            }
        }
#pragma unroll
        for (int s = 0; s < 8; ++s) cbuf[t * 8 + s] = (int)(D[s] & 1023u);
    }
    __syncthreads();

    // ---- phase 4: fp64 exact refine (x still live in xs) ----
    const int r = t >> 2;     // row 0..63
    const int q = t & 3;      // c-chunk of 32
    const int n = rowBase + r;

    double dist[8]; int es[8];
#pragma unroll
    for (int s = 0; s < 8; ++s) {
        int e = cbuf[r * 8 + s];
        es[s] = e;
        const float4* er = (const float4*)(emb + (size_t)e * DD + q * 32);
        double acc = 0.0;
#pragma unroll
        for (int u = 0; u < 8; ++u) {
            float4 ev = er[u];
            int c0 = q * 32 + u * 4;
            double a0 = (double)xs[(c0 + 0) * 66 + r] - (double)ev.x;
            double a1 = (double)xs[(c0 + 1) * 66 + r] - (double)ev.y;
            double a2 = (double)xs[(c0 + 2) * 66 + r] - (double)ev.z;
            double a3 = (double)xs[(c0 + 3) * 66 + r] - (double)ev.w;
            acc += a0 * a0 + a1 * a1 + a2 * a2 + a3 * a3;
        }
        acc += __shfl_xor(acc, 1);
        acc += __shfl_xor(acc, 2);
        dist[s] = acc;
    }

    if (q == 0) {
        unsigned usedm = 0;
        int out_idx[3];
        double d_top1 = 0.0;
#pragma unroll
        for (int p = 0; p < 3; ++p) {
            double bd = 1.0e300; int bi = 0x7fffffff, bs = 0;
#pragma unroll
            for (int s = 0; s < 8; ++s) {
                if ((usedm >> s) & 1u) continue;
                if (dist[s] < bd || (dist[s] == bd && es[s] < bi)) {
                    bd = dist[s]; bi = es[s]; bs = s;
                }
            }
            usedm |= (1u << bs);
            out_idx[p] = bi;
            if (p == 0) d_top1 = bd;
        }
        s_top[0][r] = out_idx[0];
        s_top[1][r] = out_idx[1];
        s_top[2][r] = out_idx[2];
        atomicAdd(&hist[out_idx[2]], 1);
        lsum[r] = d_top1;
    }
    __syncthreads();
    if (t < 8) {
        double a = 0.0;
#pragma unroll
        for (int i2 = 0; i2 < 8; ++i2) a += lsum[t * 8 + i2];
        lsum[t] = a;
    }
    __syncthreads();
    if (t == 0) {
        double a = 0.0;
#pragma unroll
        for (int i2 = 0; i2 < 8; ++i2) a += lsum[i2];
        partials[blockIdx.x] = a;
    }

    // ---- phase 5: fused output writes (s_top is barrier-protected above) ----
    // (a) quantized_nchw: lanes cover hw -> contiguous 256B store runs;
    //     reads are 64-way scattered 4B from L2-hot emb (512KB).
    {
        float* dq = out + OFF_QUANT + (size_t)b * (CC * HW) + hw0;
        const int rq = t & 63, cg = t >> 6;
        const float* erow = emb + (size_t)s_top[0][rq] * DD;
#pragma unroll 8
        for (int c = cg * 32; c < cg * 32 + 32; ++c)
            dq[(size_t)c * HW + rq] = erow[c];
    }
    // (b) top_k_quantized: value == quant_k == emb gather; contiguous 512B
    //     runs per wave-instr on both read (L2-hot) and write.
    {
        const f32x2* e2 = (const f32x2*)emb;
        f32x2* dt = (f32x2*)(out + OFF_TOPK);
#pragma unroll 4
        for (int u = 0; u < 48; ++u) {
            int idx = u * 256 + t;          // 12288 = 3k * 64r * 64c2
            int k  = idx >> 12;
            int rr = (idx >> 6) & 63;
            int c2 = idx & 63;
            int e  = s_top[k][rr];
            dt[(size_t)k * 2097152 + (size_t)(rowBase + rr) * 64 + c2] = e2[e * 64 + c2];
        }
    }
    // (c) encodings: zero-fill f32x2 (contiguous 2KB wave-runs), then the
    //     64 one-hot fixups after a barrier (vmcnt(0) drain orders them).
    {
        f32x2* de = (f32x2*)(out + OFF_ENC) + (size_t)rowBase * 512;
        const f32x2 z = {0.f, 0.f};
#pragma unroll 8
        for (int u = 0; u < 128; ++u)
            de[u * 256 + t] = z;
    }
    __syncthreads();
    if (t < 64)
        out[OFF_ENC + (size_t)(rowBase + t) * 1024 + s_top[2][t]] = 1.0f;
}

// ---------------------------------------------------------------------------
// kFin: finalize loss (512 fp64 partials) + perplexity (1024-bin hist).
// ---------------------------------------------------------------------------
__global__ __launch_bounds__(256) void kFin(
    const double* __restrict__ partials, const int* __restrict__ hist,
    float* __restrict__ out)
{
    __shared__ double sred[256];
    const int t = threadIdx.x;
    sred[t] = partials[t] + partials[t + 256];
    __syncthreads();
    for (int s = 128; s > 0; s >>= 1) {
        if (t < s) sred[t] += sred[t + s];
        __syncthreads();
    }
    if (t == 0) out[0] = (float)(0.25 * sred[0] / 4194304.0);
    __syncthreads();
    double s2 = 0.0;
#pragma unroll
    for (int i = 0; i < 4; ++i) {
        double p = (double)hist[t + i * 256] * (1.0 / 32768.0);
        s2 += p * log(p + 1e-10);
    }
    sred[t] = s2;
    __syncthreads();
    for (int s = 128; s > 0; s >>= 1) {
        if (t < s) sred[t] += sred[t + s];
        __syncthreads();
    }
    if (t == 0) out[OFF_PERP] = (float)exp(-sred[0]);
}

extern "C" void kernel_launch(void* const* d_in, const int* in_sizes, int n_in,
                              void* d_out, int out_size, void* d_ws, size_t ws_size,
                              hipStream_t stream)
{
    const float* in  = (const float*)d_in[0];
    const float* emb = (const float*)d_in[1];
    float* out = (float*)d_out;
    char*  ws  = (char*)d_ws;

    double* partials = (double*)(ws + WS_PARTIALS);
    int*    hist     = (int*)(ws + WS_HIST);
    ushort* embbf    = (ushort*)(ws + WS_EMBBF);
    float*  enorm    = (float*)(ws + WS_ENORM);

    kP_emb<<<dim3(16),  dim3(256), 0, stream>>>(emb, embbf, enorm, hist);
    kFull <<<dim3(512), dim3(256), 0, stream>>>(in, emb, embbf, enorm, hist, partials, out);
    kFin  <<<dim3(1),   dim3(256), 0, stream>>>(partials, hist, out);
}